// Round 20
// baseline (286.889 us; speedup 1.0000x reference)
//
#include <hip/hip_runtime.h>
#include <hip/hip_bf16.h>
#include <hip/hip_fp16.h>
#include <math.h>

#define NN   50000
#define NE   1600000
#define EP   (NE + NN)       // edges + self loops = 1,650,000
#define NB   256
#define BK_SH 6              // 64 dsts per bucket
#define BKN  (1 << BK_SH)
#define NBKT ((NN + BKN - 1) >> BK_SH)   // 782
#define CAP_SH 12            // 4096 entries per bucket region (mean 2046)
#define CAP  (1 << CAP_SH)
#define ET   8               // edges per thread in bucket part (short chains)
#define EB   (256 * ET)      // 2048 edges per block
#define EBLK ((NE + EB - 1) / EB)    // 782 blocks
#define G1   ((NN + 31) / 32)        // 1563 gemm1 blocks

__device__ __forceinline__ float elu_f(float x)   { return x > 0.0f ? x : expm1f(x); }
// leaky_relu(x, 0.2) == max(x, 0.2x) since 0.2 > 0
__device__ __forceinline__ float lrelu_f(float x) { return fmaxf(x, 0.2f * x); }

// packed fp16 via native clang ext-vector ops
typedef _Float16 f16x2 __attribute__((ext_vector_type(2)));

// ---------------- fused: gemm1 (blocks < G1) ∥ bucket scatter (rest) -----------
__global__ __launch_bounds__(256) void k_gemm1_bucket(
    const float* __restrict__ x, const float* __restrict__ wl,
    const float* __restrict__ bl, const float* __restrict__ wr,
    const float* __restrict__ br, __half* __restrict__ xl1, float* __restrict__ xr1,
    const int* __restrict__ ei, int* __restrict__ bcursor,
    unsigned int* __restrict__ bb)
{
    __shared__ float xs[32 * 64];
    __shared__ int lh[NBKT];
    __shared__ int cur[NBKT];
    const int tid = threadIdx.x;

    if (blockIdx.x < G1) {
        const int n0  = blockIdx.x * 32;
        const int nrem = min(32, NN - n0);

        const float4* xg = (const float4*)(x + (size_t)n0 * 64);
        float4* xs4 = (float4*)xs;
        const int lim4 = nrem * 16;
        for (int i = tid; i < lim4; i += 256) xs4[i] = xg[i];
        __syncthreads();

        const int g  = tid >> 6;        // 0..3 -> rows 8g..8g+7
        const int c0 = (tid & 63) * 4;  // 0..252
        const bool isl = (c0 < 128);
        const float* w  = isl ? wl : wr;
        const float* b  = isl ? bl : br;
        const int    cw = isl ? c0 : (c0 - 128);

        float4 acc[8];
#pragma unroll
        for (int r = 0; r < 8; ++r) acc[r] = make_float4(0.f, 0.f, 0.f, 0.f);

        for (int k4 = 0; k4 < 16; ++k4) {
            const float4 w0 = *(const float4*)&w[(k4*4+0)*128 + cw];
            const float4 w1 = *(const float4*)&w[(k4*4+1)*128 + cw];
            const float4 w2 = *(const float4*)&w[(k4*4+2)*128 + cw];
            const float4 w3 = *(const float4*)&w[(k4*4+3)*128 + cw];
#pragma unroll
            for (int r = 0; r < 8; ++r) {
                const float4 xv = xs4[(g*8+r)*16 + k4];
                acc[r].x += xv.x*w0.x + xv.y*w1.x + xv.z*w2.x + xv.w*w3.x;
                acc[r].y += xv.x*w0.y + xv.y*w1.y + xv.z*w2.y + xv.w*w3.y;
                acc[r].z += xv.x*w0.z + xv.y*w1.z + xv.z*w2.z + xv.w*w3.z;
                acc[r].w += xv.x*w0.w + xv.y*w1.w + xv.z*w2.w + xv.w*w3.w;
            }
        }
        const float4 bv = *(const float4*)&b[cw];
#pragma unroll
        for (int r = 0; r < 8; ++r) {
            const int row = g*8 + r;
            if (row < nrem) {
                float4 o = make_float4(acc[r].x + bv.x, acc[r].y + bv.y,
                                       acc[r].z + bv.z, acc[r].w + bv.w);
                if (isl) {
                    __half2* dst = (__half2*)&xl1[(size_t)(n0 + row) * 128 + cw];
                    dst[0] = __floats2half2_rn(o.x, o.y);
                    dst[1] = __floats2half2_rn(o.z, o.w);
                } else {
                    *(float4*)&xr1[(size_t)(n0 + row) * 128 + cw] = o;
                }
            }
        }
    } else {
        // bucket: scatter packed u32 ((d&63)<<17 | src); bcursor memset to 0
        const int bid = blockIdx.x - G1;
        for (int i = tid; i < NBKT; i += 256) lh[i] = 0;
        __syncthreads();

        const int t = bid * 256 + tid;
        const bool act = (t * ET < NE);
        int4 dreg[ET / 4];
        if (act) {
            const int4* dp = (const int4*)&ei[NE + t * ET];
#pragma unroll
            for (int q = 0; q < ET / 4; ++q) {
                dreg[q] = dp[q];
                atomicAdd(&lh[dreg[q].x >> BK_SH], 1);
                atomicAdd(&lh[dreg[q].y >> BK_SH], 1);
                atomicAdd(&lh[dreg[q].z >> BK_SH], 1);
                atomicAdd(&lh[dreg[q].w >> BK_SH], 1);
            }
        }
        __syncthreads();
        for (int i = tid; i < NBKT; i += 256) {
            int h = lh[i];
            if (h > 0) cur[i] = (i << CAP_SH) + atomicAdd(&bcursor[i], h);
        }
        __syncthreads();
        if (act) {
            const int4* sp = (const int4*)&ei[t * ET];
#pragma unroll
            for (int q = 0; q < ET / 4; ++q) {
                int4 s = sp[q];
                int4 d = dreg[q];
                int bkt, p;
                bkt = d.x >> BK_SH; p = atomicAdd(&cur[bkt], 1);
                if (p < ((bkt + 1) << CAP_SH))
                    bb[p] = ((unsigned)(d.x & (BKN-1)) << 17) | (unsigned)s.x;
                bkt = d.y >> BK_SH; p = atomicAdd(&cur[bkt], 1);
                if (p < ((bkt + 1) << CAP_SH))
                    bb[p] = ((unsigned)(d.y & (BKN-1)) << 17) | (unsigned)s.y;
                bkt = d.z >> BK_SH; p = atomicAdd(&cur[bkt], 1);
                if (p < ((bkt + 1) << CAP_SH))
                    bb[p] = ((unsigned)(d.z & (BKN-1)) << 17) | (unsigned)s.z;
                bkt = d.w >> BK_SH; p = atomicAdd(&cur[bkt], 1);
                if (p < ((bkt + 1) << CAP_SH))
                    bb[p] = ((unsigned)(d.w & (BKN-1)) << 17) | (unsigned)s.w;
            }
        }
    }
}

// ---------------- conv1 + fused GEMM2, bucket-local CSR ------------------------
// One block (512 thr = 8 waves) per bucket of 64 dsts. Block rebuilds the
// bucket's CSR in LDS from bb (count -> scan -> scatter), then each wave
// processes 8 dsts: fp16 gather + packed-fp16 score + fp32 accumulate,
// wave-local gemm2 epilogue (no barrier: h1rows region is per-wave).
// Replaces k_bfinal + global slist/rowp entirely.
__global__ __launch_bounds__(512) void k_conv1_agg(
    const __half* __restrict__ xl1, const float* __restrict__ xr1,
    const float* __restrict__ att, const float* __restrict__ bias1,
    const unsigned int* __restrict__ bb, const int* __restrict__ bcursor,
    const float* __restrict__ wl2, const float* __restrict__ bl2,
    const float* __restrict__ wr2, const float* __restrict__ br2,
    __half* __restrict__ xl2, float* __restrict__ xr2)
{
    __shared__ float wcombt[32 * 132];   // [j][c] transposed, stride 132
    __shared__ float bcomb[32];
    __shared__ float h1rows[8 * 128];
    __shared__ int lcnt[BKN], lcur[BKN];
    __shared__ int lrowp[BKN + 1];
    __shared__ int lsl[CAP + BKN];       // bucket slist (edges + self-loops)
    const int tid = threadIdx.x;
    const int b = blockIdx.x;
    const int db0 = b << BK_SH;
    const int dn  = min(BKN, NN - db0);
    const int count = min(bcursor[b], CAP);
    const unsigned int* src = bb + ((size_t)b << CAP_SH);

    // stage gemm2 weights transposed
    for (int i = tid; i < 2048; i += 512) {
        const int cc = i >> 4, jj = i & 15;
        wcombt[jj * 132 + cc]        = wl2[i];
        wcombt[(16 + jj) * 132 + cc] = wr2[i];
    }
    if (tid < 16) { bcomb[tid] = bl2[tid]; bcomb[16 + tid] = br2[tid]; }

    // ---- bucket-local CSR build ----
    int selfc = 0;
    if (tid < BKN) {
        selfc = (tid < dn) ? 1 : 0;     // self-loop
        lcnt[tid] = selfc;
    }
    __syncthreads();
    for (int i = tid; i < count; i += 512)
        atomicAdd(&lcnt[src[i] >> 17], 1);
    __syncthreads();
    int orig = 0;
    if (tid < BKN) orig = lcnt[tid];
    for (int ofs = 1; ofs < BKN; ofs <<= 1) {
        int v = 0;
        if (tid < BKN && tid >= ofs) v = lcnt[tid - ofs];
        __syncthreads();
        if (tid < BKN) lcnt[tid] += v;
        __syncthreads();
    }
    if (tid < BKN) {
        const int ex = lcnt[tid] - orig;
        lrowp[tid] = ex;
        lcur[tid] = ex + 1;             // slot 0 reserved for self-loop
        if (tid < dn) lsl[ex] = db0 + tid;
        if (tid == BKN - 1) lrowp[BKN] = lcnt[tid];
    }
    __syncthreads();
    for (int i = tid; i < count; i += 512) {
        const unsigned u = src[i];
        const int p = atomicAdd(&lcur[u >> 17], 1);
        lsl[p] = (int)(u & 0x1FFFFu);
    }
    __syncthreads();

    // ---- aggregation: 8 waves x 8 dsts ----
    const int wv = tid >> 6, lane = tid & 63;
    const int h = lane >> 3, e = lane & 7;
    const int cb = h * 16;
    const f16x2 c02 = {(_Float16)0.2f, (_Float16)0.2f};

    for (int di = 0; di < 8; ++di) {
        const int dloc = wv * 8 + di;
        if (dloc >= dn) break;
        const int d = db0 + dloc;

        f16x2 xrh[8], ath[8];
        {
            const float4* xrp = (const float4*)&xr1[(size_t)d * 128 + cb];
            const float4* atp = (const float4*)&att[cb];
#pragma unroll
            for (int q = 0; q < 4; ++q) {
                float4 a4 = xrp[q];
                xrh[2*q]   = (f16x2){(_Float16)a4.x, (_Float16)a4.y};
                xrh[2*q+1] = (f16x2){(_Float16)a4.z, (_Float16)a4.w};
                float4 b4 = atp[q];
                ath[2*q]   = (f16x2){(_Float16)b4.x, (_Float16)b4.y};
                ath[2*q+1] = (f16x2){(_Float16)b4.z, (_Float16)b4.w};
            }
        }
        const int beg = lrowp[dloc];
        const int deg = lrowp[dloc + 1] - beg;

        float den = 0.f;
        float a[16];
#pragma unroll
        for (int c = 0; c < 16; ++c) a[c] = 0.f;

        for (int idx0 = e; idx0 < deg; idx0 += 16) {
            const int s0 = lsl[beg + idx0];          // LDS broadcast per head
            const bool e1 = (idx0 + 8 < deg);
            const int s1 = e1 ? lsl[beg + idx0 + 8] : 0;
            float4 p0, p1, q0, q1;
            {
                const float4* vp = (const float4*)(xl1 + (size_t)s0 * 128 + cb);
                p0 = vp[0]; p1 = vp[1];
            }
            if (e1) {
                const float4* vp = (const float4*)(xl1 + (size_t)s1 * 128 + cb);
                q0 = vp[0]; q1 = vp[1];
            }
            {
                const f16x2* hh = (const f16x2*)&p0;
                const f16x2* hg = (const f16x2*)&p1;
                float s = 0.f;
#pragma unroll
                for (int q = 0; q < 4; ++q) {
                    f16x2 t = hh[q] + xrh[q];
                    t = __builtin_elementwise_max(t, t * c02);
                    s = __builtin_amdgcn_fdot2(ath[q], t, s, false);
                }
#pragma unroll
                for (int q = 0; q < 4; ++q) {
                    f16x2 t = hg[q] + xrh[4+q];
                    t = __builtin_elementwise_max(t, t * c02);
                    s = __builtin_amdgcn_fdot2(ath[4+q], t, s, false);
                }
                const float w = __expf(fminf(s, 80.f));
                den += w;
#pragma unroll
                for (int q = 0; q < 4; ++q) {
                    a[2*q]     += w * (float)hh[q].x;
                    a[2*q+1]   += w * (float)hh[q].y;
                    a[8+2*q]   += w * (float)hg[q].x;
                    a[8+2*q+1] += w * (float)hg[q].y;
                }
            }
            if (e1) {
                const f16x2* hh = (const f16x2*)&q0;
                const f16x2* hg = (const f16x2*)&q1;
                float s = 0.f;
#pragma unroll
                for (int q = 0; q < 4; ++q) {
                    f16x2 t = hh[q] + xrh[q];
                    t = __builtin_elementwise_max(t, t * c02);
                    s = __builtin_amdgcn_fdot2(ath[q], t, s, false);
                }
#pragma unroll
                for (int q = 0; q < 4; ++q) {
                    f16x2 t = hg[q] + xrh[4+q];
                    t = __builtin_elementwise_max(t, t * c02);
                    s = __builtin_amdgcn_fdot2(ath[4+q], t, s, false);
                }
                const float w = __expf(fminf(s, 80.f));
                den += w;
#pragma unroll
                for (int q = 0; q < 4; ++q) {
                    a[2*q]     += w * (float)hh[q].x;
                    a[2*q+1]   += w * (float)hh[q].y;
                    a[8+2*q]   += w * (float)hg[q].x;
                    a[8+2*q+1] += w * (float)hg[q].y;
                }
            }
        }

        // sum den over the 8 e-lanes of this head
        den += __shfl_xor(den, 1);
        den += __shfl_xor(den, 2);
        den += __shfl_xor(den, 4);

        // reduce-scatter a[16] over e-lanes
        const bool b0 = (e & 1), b1 = (e & 2), b2 = (e & 4);
        float t1[8], u1[8];
#pragma unroll
        for (int j = 0; j < 8; ++j) {
            t1[j] = b0 ? a[j + 8] : a[j];
            u1[j] = b0 ? a[j] : a[j + 8];
        }
#pragma unroll
        for (int j = 0; j < 8; ++j) t1[j] += __shfl_xor(u1[j], 1);
        float t2[4], u2[4];
#pragma unroll
        for (int j = 0; j < 4; ++j) {
            t2[j] = b1 ? t1[j + 4] : t1[j];
            u2[j] = b1 ? t1[j] : t1[j + 4];
        }
#pragma unroll
        for (int j = 0; j < 4; ++j) t2[j] += __shfl_xor(u2[j], 2);
        float t3[2], u3[2];
#pragma unroll
        for (int j = 0; j < 2; ++j) {
            t3[j] = b2 ? t2[j + 2] : t2[j];
            u3[j] = b2 ? t2[j] : t2[j + 2];
        }
#pragma unroll
        for (int j = 0; j < 2; ++j) t3[j] += __shfl_xor(u3[j], 4);

        const int c0 = (b0 ? 8 : 0) + (b1 ? 4 : 0) + (b2 ? 2 : 0);
        const float inv = 1.0f / (den + 1e-16f);
        const int c = cb + c0;
        const float o0 = elu_f(t3[0] * inv + bias1[c]);
        const float o1 = elu_f(t3[1] * inv + bias1[c + 1]);

        // ---- wave-local gemm2 epilogue (no barrier: only this wave's region) --
        *(float2*)&h1rows[wv * 128 + c] = make_float2(o0, o1);
        {
            const int j = lane & 31;
            const int half = lane >> 5;
            const float* hr = &h1rows[wv * 128 + half * 64];
            const float* wc = &wcombt[j * 132 + half * 64];
            float sum = 0.f;
#pragma unroll
            for (int cc = 0; cc < 64; cc += 4) {
                const float4 hv = *(const float4*)&hr[cc];
                const float4 wv4 = *(const float4*)&wc[cc];
                sum += hv.x*wv4.x + hv.y*wv4.y + hv.z*wv4.z + hv.w*wv4.w;
            }
            sum += __shfl_xor(sum, 32);
            if (half == 0) {
                sum += bcomb[j];
                if (j < 16) xl2[(size_t)d * 16 + j] = __float2half(sum);
                else        xr2[(size_t)d * 16 + (j - 16)] = sum;
            }
        }
    }
}

// ---------------- conv2, bucket-local CSR: one block (512) per bucket ----------
__global__ __launch_bounds__(512) void k_conv2_agg(
    const __half* __restrict__ xl2, const float* __restrict__ xr2,
    const float* __restrict__ att, const float* __restrict__ bias2,
    const unsigned int* __restrict__ bb, const int* __restrict__ bcursor,
    float* __restrict__ h2)
{
    __shared__ int lcnt[BKN], lcur[BKN];
    __shared__ int lrowp[BKN + 1];
    __shared__ int lsl[CAP + BKN];
    const int tid = threadIdx.x;
    const int b = blockIdx.x;
    const int db0 = b << BK_SH;
    const int dn  = min(BKN, NN - db0);
    const int count = min(bcursor[b], CAP);
    const unsigned int* src = bb + ((size_t)b << CAP_SH);

    // ---- bucket-local CSR build ----
    int selfc = 0;
    if (tid < BKN) {
        selfc = (tid < dn) ? 1 : 0;
        lcnt[tid] = selfc;
    }
    __syncthreads();
    for (int i = tid; i < count; i += 512)
        atomicAdd(&lcnt[src[i] >> 17], 1);
    __syncthreads();
    int orig = 0;
    if (tid < BKN) orig = lcnt[tid];
    for (int ofs = 1; ofs < BKN; ofs <<= 1) {
        int v = 0;
        if (tid < BKN && tid >= ofs) v = lcnt[tid - ofs];
        __syncthreads();
        if (tid < BKN) lcnt[tid] += v;
        __syncthreads();
    }
    if (tid < BKN) {
        const int ex = lcnt[tid] - orig;
        lrowp[tid] = ex;
        lcur[tid] = ex + 1;
        if (tid < dn) lsl[ex] = db0 + tid;
        if (tid == BKN - 1) lrowp[BKN] = lcnt[tid];
    }
    __syncthreads();
    for (int i = tid; i < count; i += 512) {
        const unsigned u = src[i];
        const int p = atomicAdd(&lcur[u >> 17], 1);
        lsl[p] = (int)(u & 0x1FFFFu);
    }
    __syncthreads();

    // ---- aggregation: 8 waves x 8 dsts, one edge per lane ----
    const int wv = tid >> 6, lane = tid & 63;
    const f16x2 c02 = {(_Float16)0.2f, (_Float16)0.2f};

    for (int di = 0; di < 8; ++di) {
        const int dloc = wv * 8 + di;
        if (dloc >= dn) break;
        const int d = db0 + dloc;

        f16x2 xrh[8], ath[8];
        {
            const float4* xrp = (const float4*)&xr2[(size_t)d * 16];
            const float4* atp = (const float4*)&att[0];
#pragma unroll
            for (int q = 0; q < 4; ++q) {
                float4 a4 = xrp[q];
                xrh[2*q]   = (f16x2){(_Float16)a4.x, (_Float16)a4.y};
                xrh[2*q+1] = (f16x2){(_Float16)a4.z, (_Float16)a4.w};
                float4 b4 = atp[q];
                ath[2*q]   = (f16x2){(_Float16)b4.x, (_Float16)b4.y};
                ath[2*q+1] = (f16x2){(_Float16)b4.z, (_Float16)b4.w};
            }
        }
        const int beg = lrowp[dloc];
        const int deg = lrowp[dloc + 1] - beg;

        float den = 0.f;
        float a[16];
#pragma unroll
        for (int c = 0; c < 16; ++c) a[c] = 0.f;

        for (int j = lane; j < deg; j += 64) {
            const int s0 = lsl[beg + j];
            const float4* vp = (const float4*)(xl2 + (size_t)s0 * 16);
            const float4 r0 = vp[0], r1 = vp[1];
            const f16x2* hh = (const f16x2*)&r0;
            const f16x2* hg = (const f16x2*)&r1;
            float s = 0.f;
#pragma unroll
            for (int q = 0; q < 4; ++q) {
                f16x2 t = hh[q] + xrh[q];
                t = __builtin_elementwise_max(t, t * c02);
                s = __builtin_amdgcn_fdot2(ath[q], t, s, false);
            }
#pragma unroll
            for (int q = 0; q < 4; ++q) {
                f16x2 t = hg[q] + xrh[4+q];
                t = __builtin_elementwise_max(t, t * c02);
                s = __builtin_amdgcn_fdot2(ath[4+q], t, s, false);
            }
            const float w = __expf(fminf(s, 80.f));
            den += w;
#pragma unroll
            for (int q = 0; q < 4; ++q) {
                a[2*q]     += w * (float)hh[q].x;
                a[2*q+1]   += w * (float)hh[q].y;
                a[8+2*q]   += w * (float)hg[q].x;
                a[8+2*q+1] += w * (float)hg[q].y;
            }
        }

        // full-wave den sum
        den += __shfl_xor(den, 1);
        den += __shfl_xor(den, 2);
        den += __shfl_xor(den, 4);
        den += __shfl_xor(den, 8);
        den += __shfl_xor(den, 16);
        den += __shfl_xor(den, 32);

        // reduce-scatter a[16] over lane bits 0..3, then plain-sum xor 16,32
        const bool b0 = (lane & 1), b1 = (lane & 2), b2 = (lane & 4), b3 = (lane & 8);
        float t1[8], u1[8];
#pragma unroll
        for (int j = 0; j < 8; ++j) {
            t1[j] = b0 ? a[j + 8] : a[j];
            u1[j] = b0 ? a[j] : a[j + 8];
        }
#pragma unroll
        for (int j = 0; j < 8; ++j) t1[j] += __shfl_xor(u1[j], 1);
        float t2[4], u2[4];
#pragma unroll
        for (int j = 0; j < 4; ++j) {
            t2[j] = b1 ? t1[j + 4] : t1[j];
            u2[j] = b1 ? t1[j] : t1[j + 4];
        }
#pragma unroll
        for (int j = 0; j < 4; ++j) t2[j] += __shfl_xor(u2[j], 2);
        float t3[2], u3[2];
#pragma unroll
        for (int j = 0; j < 2; ++j) {
            t3[j] = b2 ? t2[j + 2] : t2[j];
            u3[j] = b2 ? t2[j] : t2[j + 2];
        }
#pragma unroll
        for (int j = 0; j < 2; ++j) t3[j] += __shfl_xor(u3[j], 4);
        float t4 = b3 ? t3[1] : t3[0];
        float u4 = b3 ? t3[0] : t3[1];
        t4 += __shfl_xor(u4, 8);
        t4 += __shfl_xor(t4, 16);
        t4 += __shfl_xor(t4, 32);

        if (lane < 16) {
            const int c = (b0 ? 8 : 0) + (b1 ? 4 : 0) + (b2 ? 2 : 0) + (b3 ? 1 : 0);
            const float inv = 1.0f / (den + 1e-16f);
            h2[(size_t)d * 16 + c] = elu_f(t4 * inv + bias2[c]);
        }
    }
}

// ---------------- fused mean-pool + MLP: one block per graph -------------------
__global__ __launch_bounds__(256) void k_pool_mlp(
    const float* __restrict__ h2, const int* __restrict__ batch,
    const float* __restrict__ w1, const float* __restrict__ b1,
    const float* __restrict__ w2, const float* __restrict__ b2,
    const float* __restrict__ w3, const float* __restrict__ b3,
    float* __restrict__ out)
{
    __shared__ int se[2];
    __shared__ float sm[256];
    __shared__ float hb[16], t1s[32], t2s[16];
    const int b = blockIdx.x, tid = threadIdx.x;
    if (tid < 2) {
        int key = b + tid, lo = 0, hi = NN;
        while (lo < hi) {
            int mid = (lo + hi) >> 1;
            if (batch[mid] < key) lo = mid + 1; else hi = mid;
        }
        se[tid] = lo;
    }
    __syncthreads();
    const int s = se[0], e = se[1];
    const int c = tid & 15, slot = tid >> 4;
    float acc = 0.f;
    for (int n = s + slot; n < e; n += 16) acc += h2[(size_t)n * 16 + c];
    sm[tid] = acc;
    __syncthreads();
    for (int ofs = 128; ofs >= 16; ofs >>= 1) {
        if (tid < ofs) sm[tid] += sm[tid + ofs];
        __syncthreads();
    }
    if (tid < 16) hb[tid] = sm[tid] / fmaxf((float)(e - s), 1.0f);
    __syncthreads();
    if (tid < 32) {
        float v = b1[tid];
        for (int k = 0; k < 16; ++k) v += hb[k] * w1[k * 32 + tid];
        t1s[tid] = elu_f(v);
    }
    __syncthreads();
    if (tid < 16) {
        float v = b2[tid];
        for (int k = 0; k < 32; ++k) v += t1s[k] * w2[k * 16 + tid];
        t2s[tid] = elu_f(v);
    }
    __syncthreads();
    if (tid < 32) {
        float v = b3[tid];
        for (int k = 0; k < 16; ++k) v += t2s[k] * w3[k * 32 + tid];
        out[b * 32 + tid] = v;
    }
}

// ---------------- launch -------------------------------------------------------
extern "C" void kernel_launch(void* const* d_in, const int* in_sizes, int n_in,
                              void* d_out, int out_size, void* d_ws, size_t ws_size,
                              hipStream_t stream)
{
    const float* x     = (const float*)d_in[0];
    const int*   ei    = (const int*)d_in[1];
    const int*   batch = (const int*)d_in[2];
    const float* wl1   = (const float*)d_in[3];
    const float* bl1   = (const float*)d_in[4];
    const float* wr1   = (const float*)d_in[5];
    const float* br1   = (const float*)d_in[6];
    const float* att1  = (const float*)d_in[7];
    const float* bias1 = (const float*)d_in[8];
    const float* wl2   = (const float*)d_in[9];
    const float* bl2   = (const float*)d_in[10];
    const float* wr2   = (const float*)d_in[11];
    const float* br2   = (const float*)d_in[12];
    const float* att2  = (const float*)d_in[13];
    const float* bias2 = (const float*)d_in[14];
    const float* wm1   = (const float*)d_in[15];
    const float* bm1   = (const float*)d_in[16];
    const float* wm2   = (const float*)d_in[17];
    const float* bm2   = (const float*)d_in[18];
    const float* wm3   = (const float*)d_in[19];
    const float* bm3   = (const float*)d_in[20];
    float* out = (float*)d_out;

    char* base = (char*)d_ws;
    size_t off = 0;
    auto alloc = [&](size_t bytes) -> void* {
        void* p = base + off;
        off += (bytes + 255) & ~(size_t)255;
        return p;
    };
    __half* xl1  = (__half*)alloc((size_t)NN * 128 * 2);
    float* xr1   = (float*)alloc((size_t)NN * 128 * 4);
    unsigned int* bb = (unsigned int*)alloc((size_t)NBKT * CAP * 4);
    int*   bcursor=(int*)  alloc((size_t)NBKT * 4);
    __half* xl2  = (__half*)alloc((size_t)NN * 16 * 2);
    float* xr2   = (float*)alloc((size_t)NN * 16 * 4);
    float* h2    = (float*)alloc((size_t)NN * 16 * 4);

    (void)hipMemsetAsync(bcursor, 0, (size_t)NBKT * 4, stream);
    k_gemm1_bucket<<<G1 + EBLK, 256, 0, stream>>>(x, wl1, bl1, wr1, br1, xl1, xr1,
                                                  ei, bcursor, bb);
    k_conv1_agg<<<NBKT, 512, 0, stream>>>(xl1, xr1, att1, bias1, bb, bcursor,
                                          wl2, bl2, wr2, br2, xl2, xr2);
    k_conv2_agg<<<NBKT, 512, 0, stream>>>(xl2, xr2, att2, bias2, bb, bcursor, h2);
    k_pool_mlp<<<NB, 256, 0, stream>>>(h2, batch, wm1, bm1, wm2, bm2, wm3, bm3, out);
}

// Round 21
// 280.210 us; speedup vs baseline: 1.0238x; 1.0238x over previous
//
#include <hip/hip_runtime.h>
#include <hip/hip_bf16.h>
#include <hip/hip_fp16.h>
#include <math.h>

#define NN   50000
#define NE   1600000
#define EP   (NE + NN)       // edges + self loops = 1,650,000
#define NB   256
#define BK_SH 6              // 64 dsts per bucket
#define BKN  (1 << BK_SH)
#define NBKT ((NN + BKN - 1) >> BK_SH)   // 782
#define CAP_SH 12            // 4096 entries per bucket region (mean 2046)
#define CAP  (1 << CAP_SH)
#define ET   8               // edges per thread in bucket part (short chains)
#define EB   (256 * ET)      // 2048 edges per block
#define EBLK ((NE + EB - 1) / EB)    // 782 blocks
#define G1   ((NN + 31) / 32)        // 1563 gemm1 blocks

__device__ __forceinline__ float elu_f(float x)   { return x > 0.0f ? x : expm1f(x); }
// leaky_relu(x, 0.2) == max(x, 0.2x) since 0.2 > 0
__device__ __forceinline__ float lrelu_f(float x) { return fmaxf(x, 0.2f * x); }

// packed fp16 via native clang ext-vector ops (avoids __hmax2/__hmul2 overload
// collision between hip_fp16.h and hip_bf16.h on ROCm 7.2)
typedef _Float16 f16x2 __attribute__((ext_vector_type(2)));

// ---------------- fused: gemm1 (blocks < G1) ∥ bucket scatter (rest) -----------
__global__ __launch_bounds__(256) void k_gemm1_bucket(
    const float* __restrict__ x, const float* __restrict__ wl,
    const float* __restrict__ bl, const float* __restrict__ wr,
    const float* __restrict__ br, __half* __restrict__ xl1, float* __restrict__ xr1,
    const int* __restrict__ ei, int* __restrict__ bcursor,
    unsigned int* __restrict__ bb)
{
    __shared__ float xs[32 * 64];
    __shared__ int lh[NBKT];
    __shared__ int cur[NBKT];
    const int tid = threadIdx.x;

    if (blockIdx.x < G1) {
        // ---------- GEMM1: xl1(half) = x@wl1+bl1, xr1(f32) = x@wr1+br1 ----------
        const int n0  = blockIdx.x * 32;
        const int nrem = min(32, NN - n0);

        const float4* xg = (const float4*)(x + (size_t)n0 * 64);
        float4* xs4 = (float4*)xs;
        const int lim4 = nrem * 16;
        for (int i = tid; i < lim4; i += 256) xs4[i] = xg[i];
        __syncthreads();

        const int g  = tid >> 6;        // 0..3 -> rows 8g..8g+7
        const int c0 = (tid & 63) * 4;  // 0..252
        const bool isl = (c0 < 128);
        const float* w  = isl ? wl : wr;
        const float* b  = isl ? bl : br;
        const int    cw = isl ? c0 : (c0 - 128);

        float4 acc[8];
#pragma unroll
        for (int r = 0; r < 8; ++r) acc[r] = make_float4(0.f, 0.f, 0.f, 0.f);

        for (int k4 = 0; k4 < 16; ++k4) {
            const float4 w0 = *(const float4*)&w[(k4*4+0)*128 + cw];
            const float4 w1 = *(const float4*)&w[(k4*4+1)*128 + cw];
            const float4 w2 = *(const float4*)&w[(k4*4+2)*128 + cw];
            const float4 w3 = *(const float4*)&w[(k4*4+3)*128 + cw];
#pragma unroll
            for (int r = 0; r < 8; ++r) {
                const float4 xv = xs4[(g*8+r)*16 + k4];
                acc[r].x += xv.x*w0.x + xv.y*w1.x + xv.z*w2.x + xv.w*w3.x;
                acc[r].y += xv.x*w0.y + xv.y*w1.y + xv.z*w2.y + xv.w*w3.y;
                acc[r].z += xv.x*w0.z + xv.y*w1.z + xv.z*w2.z + xv.w*w3.z;
                acc[r].w += xv.x*w0.w + xv.y*w1.w + xv.z*w2.w + xv.w*w3.w;
            }
        }
        const float4 bv = *(const float4*)&b[cw];
#pragma unroll
        for (int r = 0; r < 8; ++r) {
            const int row = g*8 + r;
            if (row < nrem) {
                float4 o = make_float4(acc[r].x + bv.x, acc[r].y + bv.y,
                                       acc[r].z + bv.z, acc[r].w + bv.w);
                if (isl) {
                    __half2* dst = (__half2*)&xl1[(size_t)(n0 + row) * 128 + cw];
                    dst[0] = __floats2half2_rn(o.x, o.y);
                    dst[1] = __floats2half2_rn(o.z, o.w);
                } else {
                    *(float4*)&xr1[(size_t)(n0 + row) * 128 + cw] = o;
                }
            }
        }
    } else {
        // ---------- bucket: scatter packed u32 ((d&63)<<17 | src) ---------------
        const int bid = blockIdx.x - G1;
        for (int i = tid; i < NBKT; i += 256) lh[i] = 0;
        __syncthreads();

        const int t = bid * 256 + tid;
        const bool act = (t * ET < NE);
        int4 dreg[ET / 4];
        if (act) {
            const int4* dp = (const int4*)&ei[NE + t * ET];
#pragma unroll
            for (int q = 0; q < ET / 4; ++q) {
                dreg[q] = dp[q];
                atomicAdd(&lh[dreg[q].x >> BK_SH], 1);
                atomicAdd(&lh[dreg[q].y >> BK_SH], 1);
                atomicAdd(&lh[dreg[q].z >> BK_SH], 1);
                atomicAdd(&lh[dreg[q].w >> BK_SH], 1);
            }
        }
        __syncthreads();
        for (int i = tid; i < NBKT; i += 256) {
            int h = lh[i];
            if (h > 0) cur[i] = (i << CAP_SH) + atomicAdd(&bcursor[i], h);
        }
        __syncthreads();
        if (act) {
            const int4* sp = (const int4*)&ei[t * ET];
#pragma unroll
            for (int q = 0; q < ET / 4; ++q) {
                int4 s = sp[q];
                int4 d = dreg[q];
                int bkt, p;
                bkt = d.x >> BK_SH; p = atomicAdd(&cur[bkt], 1);
                if (p < ((bkt + 1) << CAP_SH))
                    bb[p] = ((unsigned)(d.x & (BKN-1)) << 17) | (unsigned)s.x;
                bkt = d.y >> BK_SH; p = atomicAdd(&cur[bkt], 1);
                if (p < ((bkt + 1) << CAP_SH))
                    bb[p] = ((unsigned)(d.y & (BKN-1)) << 17) | (unsigned)s.y;
                bkt = d.z >> BK_SH; p = atomicAdd(&cur[bkt], 1);
                if (p < ((bkt + 1) << CAP_SH))
                    bb[p] = ((unsigned)(d.z & (BKN-1)) << 17) | (unsigned)s.z;
                bkt = d.w >> BK_SH; p = atomicAdd(&cur[bkt], 1);
                if (p < ((bkt + 1) << CAP_SH))
                    bb[p] = ((unsigned)(d.w & (BKN-1)) << 17) | (unsigned)s.w;
            }
        }
    }
}

// bfinal: one block per bucket (64 dsts). bcursor[b] holds the raw count.
__global__ __launch_bounds__(256) void k_bfinal(
    const unsigned int* __restrict__ bb, const int* __restrict__ bcursor,
    int* __restrict__ rowp, int* __restrict__ slist)
{
    __shared__ int cnt[BKN], cur[BKN];
    __shared__ int red[256];
    const int b = blockIdx.x, tid = threadIdx.x;
    const int db0 = b << BK_SH;
    const int dn  = min(BKN, NN - db0);

    // prefix over preceding buckets (<=4 iterations)
    int part = 0;
    for (int i = tid; i < b; i += 256)
        part += min(bcursor[i], CAP);
    red[tid] = part;
    __syncthreads();
    for (int ofs = 128; ofs >= 1; ofs >>= 1) {
        if (tid < ofs) red[tid] += red[tid + ofs];
        __syncthreads();
    }
    const int ebeg = red[0];
    const int count = min(bcursor[b], CAP);
    const unsigned int* src = bb + ((size_t)b << CAP_SH);
    const int out0 = ebeg + db0;

    int c0 = 0;
    if (tid < BKN) {
        c0 = (tid < dn) ? 1 : 0;       // self-loop
        cnt[tid] = c0;
    }
    __syncthreads();
    for (int i = tid; i < count; i += 256)
        atomicAdd(&cnt[src[i] >> 17], 1);
    __syncthreads();
    if (tid < BKN) c0 = cnt[tid];      // per-dst total (incl. self-loop)
    // inclusive scan of cnt[BKN]
    for (int ofs = 1; ofs < BKN; ofs <<= 1) {
        int v = 0;
        if (tid < BKN && tid >= ofs) v = cnt[tid - ofs];
        __syncthreads();
        if (tid < BKN) cnt[tid] += v;
        __syncthreads();
    }
    if (tid < BKN) {
        int ex = cnt[tid] - c0;        // exclusive
        cur[tid] = ex + 1;             // slot 0 reserved for self-loop
        if (tid < dn) {
            rowp[db0 + tid] = out0 + ex;
            slist[out0 + ex] = db0 + tid;   // self-loop
        }
    }
    if (b == 0 && tid == 0) rowp[NN] = EP;
    __syncthreads();
    for (int i = tid; i < count; i += 256) {
        unsigned u = src[i];
        int p = atomicAdd(&cur[u >> 17], 1);
        slist[out0 + p] = (int)(u & 0x1FFFFu);
    }
}

// ---------------- conv1 aggregation + fused GEMM2 (packed-fp16 scoring) --------
// Score path in packed fp16 (v_pk_add/mul/max + v_dot2_f32_f16, fp32
// accumulate inside the dot). Weighted accumulation stays fp32.
__global__ __launch_bounds__(256) void k_conv1_agg(
    const __half* __restrict__ xl1, const float* __restrict__ xr1,
    const float* __restrict__ att, const float* __restrict__ bias1,
    const int* __restrict__ rowp, const int* __restrict__ slist,
    const float* __restrict__ wl2, const float* __restrict__ bl2,
    const float* __restrict__ wr2, const float* __restrict__ br2,
    __half* __restrict__ xl2, float* __restrict__ xr2)
{
    __shared__ float wcombt[32 * 132];  // [j][c] transposed, stride 132
    __shared__ float bcomb[32];
    __shared__ float h1rows[4 * 128];
    const int tid = threadIdx.x;

    // stage gemm2 weights transposed (barrier below covers visibility)
    for (int i = tid; i < 2048; i += 256) {
        const int cc = i >> 4, jj = i & 15;
        wcombt[jj * 132 + cc]        = wl2[i];
        wcombt[(16 + jj) * 132 + cc] = wr2[i];
    }
    if (tid < 16) { bcomb[tid] = bl2[tid]; bcomb[16 + tid] = br2[tid]; }

    const int d = (blockIdx.x * 256 + tid) >> 6;   // wave id = dst (< NN always)
    const int lane = tid & 63;
    const int h = lane >> 3, e = lane & 7;
    const int cb = h * 16;

    f16x2 xrh[8], ath[8];
    {
        const float4* xrp = (const float4*)&xr1[(size_t)d * 128 + cb];
        const float4* atp = (const float4*)&att[cb];
#pragma unroll
        for (int q = 0; q < 4; ++q) {
            float4 a4 = xrp[q];
            xrh[2*q]   = (f16x2){(_Float16)a4.x, (_Float16)a4.y};
            xrh[2*q+1] = (f16x2){(_Float16)a4.z, (_Float16)a4.w};
            float4 b4 = atp[q];
            ath[2*q]   = (f16x2){(_Float16)b4.x, (_Float16)b4.y};
            ath[2*q+1] = (f16x2){(_Float16)b4.z, (_Float16)b4.w};
        }
    }
    const f16x2 c02 = {(_Float16)0.2f, (_Float16)0.2f};

    const int beg = rowp[d], end = rowp[d + 1];

    float den = 0.f;
    float a[16];
#pragma unroll
    for (int c = 0; c < 16; ++c) a[c] = 0.f;

    for (int base = beg; base < end; base += 64) {
        const int nb = min(64, end - base);
        int sv = (lane < nb) ? slist[base + lane] : 0;
        for (int c8 = 0; c8 * 8 < nb; c8 += 2) {
            const int idx0 = c8 * 8 + e;
            const int idx1 = idx0 + 8;           // <= 63 always (c8 even, <8)
            const int s0 = __shfl(sv, idx0);
            const int s1 = __shfl(sv, idx1 & 63);
            const bool e0 = (idx0 < nb), e1 = (idx1 < nb);
            float4 p0, p1, q0, q1;
            if (e0) {
                const float4* vp = (const float4*)(xl1 + (size_t)s0 * 128 + cb);
                p0 = vp[0]; p1 = vp[1];
            }
            if (e1) {
                const float4* vp = (const float4*)(xl1 + (size_t)s1 * 128 + cb);
                q0 = vp[0]; q1 = vp[1];
            }
            if (e0) {
                const f16x2* hh = (const f16x2*)&p0;   // 4 packed pairs
                const f16x2* hg = (const f16x2*)&p1;
                float s = 0.f;
#pragma unroll
                for (int q = 0; q < 4; ++q) {
                    f16x2 t = hh[q] + xrh[q];
                    t = __builtin_elementwise_max(t, t * c02);
                    s = __builtin_amdgcn_fdot2(ath[q], t, s, false);
                }
#pragma unroll
                for (int q = 0; q < 4; ++q) {
                    f16x2 t = hg[q] + xrh[4+q];
                    t = __builtin_elementwise_max(t, t * c02);
                    s = __builtin_amdgcn_fdot2(ath[4+q], t, s, false);
                }
                const float w = __expf(fminf(s, 80.f));
                den += w;
#pragma unroll
                for (int q = 0; q < 4; ++q) {
                    a[2*q]     += w * (float)hh[q].x;
                    a[2*q+1]   += w * (float)hh[q].y;
                    a[8+2*q]   += w * (float)hg[q].x;
                    a[8+2*q+1] += w * (float)hg[q].y;
                }
            }
            if (e1) {
                const f16x2* hh = (const f16x2*)&q0;
                const f16x2* hg = (const f16x2*)&q1;
                float s = 0.f;
#pragma unroll
                for (int q = 0; q < 4; ++q) {
                    f16x2 t = hh[q] + xrh[q];
                    t = __builtin_elementwise_max(t, t * c02);
                    s = __builtin_amdgcn_fdot2(ath[q], t, s, false);
                }
#pragma unroll
                for (int q = 0; q < 4; ++q) {
                    f16x2 t = hg[q] + xrh[4+q];
                    t = __builtin_elementwise_max(t, t * c02);
                    s = __builtin_amdgcn_fdot2(ath[4+q], t, s, false);
                }
                const float w = __expf(fminf(s, 80.f));
                den += w;
#pragma unroll
                for (int q = 0; q < 4; ++q) {
                    a[2*q]     += w * (float)hh[q].x;
                    a[2*q+1]   += w * (float)hh[q].y;
                    a[8+2*q]   += w * (float)hg[q].x;
                    a[8+2*q+1] += w * (float)hg[q].y;
                }
            }
        }
    }

    // sum den over the 8 e-lanes of this head
    den += __shfl_xor(den, 1);
    den += __shfl_xor(den, 2);
    den += __shfl_xor(den, 4);

    // reduce-scatter a[16] over e-lanes: each level halves the channel set
    const bool b0 = (e & 1), b1 = (e & 2), b2 = (e & 4);
    float t1[8], u1[8];
#pragma unroll
    for (int j = 0; j < 8; ++j) {
        t1[j] = b0 ? a[j + 8] : a[j];
        u1[j] = b0 ? a[j] : a[j + 8];
    }
#pragma unroll
    for (int j = 0; j < 8; ++j) t1[j] += __shfl_xor(u1[j], 1);
    float t2[4], u2[4];
#pragma unroll
    for (int j = 0; j < 4; ++j) {
        t2[j] = b1 ? t1[j + 4] : t1[j];
        u2[j] = b1 ? t1[j] : t1[j + 4];
    }
#pragma unroll
    for (int j = 0; j < 4; ++j) t2[j] += __shfl_xor(u2[j], 2);
    float t3[2], u3[2];
#pragma unroll
    for (int j = 0; j < 2; ++j) {
        t3[j] = b2 ? t2[j + 2] : t2[j];
        u3[j] = b2 ? t2[j] : t2[j + 2];
    }
#pragma unroll
    for (int j = 0; j < 2; ++j) t3[j] += __shfl_xor(u3[j], 4);

    const int c0 = (b0 ? 8 : 0) + (b1 ? 4 : 0) + (b2 ? 2 : 0);
    const float inv = 1.0f / (den + 1e-16f);
    const int c = cb + c0;                 // even -> 8B-aligned float2 store
    const float o0 = elu_f(t3[0] * inv + bias1[c]);
    const float o1 = elu_f(t3[1] * inv + bias1[c + 1]);

    // ---- fused GEMM2 epilogue (vectorized) ----
    const int wv = tid >> 6;
    *(float2*)&h1rows[wv * 128 + c] = make_float2(o0, o1);
    __syncthreads();
    {
        const int j = lane & 31;          // output column 0..31
        const int half = lane >> 5;       // channel half 0/1
        const float* hr = &h1rows[wv * 128 + half * 64];
        const float* wc = &wcombt[j * 132 + half * 64];
        float sum = 0.f;
#pragma unroll
        for (int cc = 0; cc < 64; cc += 4) {
            const float4 hv = *(const float4*)&hr[cc];
            const float4 wv4 = *(const float4*)&wc[cc];
            sum += hv.x*wv4.x + hv.y*wv4.y + hv.z*wv4.z + hv.w*wv4.w;
        }
        sum += __shfl_xor(sum, 32);
        if (half == 0) {
            sum += bcomb[j];
            if (j < 16) xl2[(size_t)d * 16 + j] = __float2half(sum);
            else        xr2[(size_t)d * 16 + (j - 16)] = sum;
        }
    }
}

// ---------------- conv2 aggregation: one EDGE per lane, packed-fp16 score ------
__global__ __launch_bounds__(256) void k_conv2_agg(
    const __half* __restrict__ xl2, const float* __restrict__ xr2,
    const float* __restrict__ att, const float* __restrict__ bias2,
    const int* __restrict__ rowp, const int* __restrict__ slist,
    float* __restrict__ h2)
{
    const int d = (blockIdx.x * 256 + threadIdx.x) >> 6;   // wave id = dst
    if (d >= NN) return;
    const int lane = threadIdx.x & 63;

    f16x2 xrh[8], ath[8];
    {
        const float4* xrp = (const float4*)&xr2[(size_t)d * 16];
        const float4* atp = (const float4*)&att[0];
#pragma unroll
        for (int q = 0; q < 4; ++q) {
            float4 a4 = xrp[q];
            xrh[2*q]   = (f16x2){(_Float16)a4.x, (_Float16)a4.y};
            xrh[2*q+1] = (f16x2){(_Float16)a4.z, (_Float16)a4.w};
            float4 b4 = atp[q];
            ath[2*q]   = (f16x2){(_Float16)b4.x, (_Float16)b4.y};
            ath[2*q+1] = (f16x2){(_Float16)b4.z, (_Float16)b4.w};
        }
    }
    const f16x2 c02 = {(_Float16)0.2f, (_Float16)0.2f};

    const int beg = rowp[d];
    const int total = rowp[d + 1] - beg;

    float den = 0.f;
    float a[16];
#pragma unroll
    for (int c = 0; c < 16; ++c) a[c] = 0.f;

    for (int j = lane; j < total; j += 64) {
        const int src = slist[beg + j];                 // coalesced
        const float4* vp = (const float4*)(xl2 + (size_t)src * 16);
        const float4 r0 = vp[0], r1 = vp[1];            // 16 halves
        const f16x2* hh = (const f16x2*)&r0;
        const f16x2* hg = (const f16x2*)&r1;
        float s = 0.f;
#pragma unroll
        for (int q = 0; q < 4; ++q) {
            f16x2 t = hh[q] + xrh[q];
            t = __builtin_elementwise_max(t, t * c02);
            s = __builtin_amdgcn_fdot2(ath[q], t, s, false);
        }
#pragma unroll
        for (int q = 0; q < 4; ++q) {
            f16x2 t = hg[q] + xrh[4+q];
            t = __builtin_elementwise_max(t, t * c02);
            s = __builtin_amdgcn_fdot2(ath[4+q], t, s, false);
        }
        const float w = __expf(fminf(s, 80.f));
        den += w;
#pragma unroll
        for (int q = 0; q < 4; ++q) {
            a[2*q]     += w * (float)hh[q].x;
            a[2*q+1]   += w * (float)hh[q].y;
            a[8+2*q]   += w * (float)hg[q].x;
            a[8+2*q+1] += w * (float)hg[q].y;
        }
    }

    // full-wave den sum
    den += __shfl_xor(den, 1);
    den += __shfl_xor(den, 2);
    den += __shfl_xor(den, 4);
    den += __shfl_xor(den, 8);
    den += __shfl_xor(den, 16);
    den += __shfl_xor(den, 32);

    // reduce-scatter a[16] over lane bits 0..3, then plain-sum xor 16,32
    const bool b0 = (lane & 1), b1 = (lane & 2), b2 = (lane & 4), b3 = (lane & 8);
    float t1[8], u1[8];
#pragma unroll
    for (int j = 0; j < 8; ++j) {
        t1[j] = b0 ? a[j + 8] : a[j];
        u1[j] = b0 ? a[j] : a[j + 8];
    }
#pragma unroll
    for (int j = 0; j < 8; ++j) t1[j] += __shfl_xor(u1[j], 1);
    float t2[4], u2[4];
#pragma unroll
    for (int j = 0; j < 4; ++j) {
        t2[j] = b1 ? t1[j + 4] : t1[j];
        u2[j] = b1 ? t1[j] : t1[j + 4];
    }
#pragma unroll
    for (int j = 0; j < 4; ++j) t2[j] += __shfl_xor(u2[j], 2);
    float t3[2], u3[2];
#pragma unroll
    for (int j = 0; j < 2; ++j) {
        t3[j] = b2 ? t2[j + 2] : t2[j];
        u3[j] = b2 ? t2[j] : t2[j + 2];
    }
#pragma unroll
    for (int j = 0; j < 2; ++j) t3[j] += __shfl_xor(u3[j], 4);
    float t4 = b3 ? t3[1] : t3[0];
    float u4 = b3 ? t3[0] : t3[1];
    t4 += __shfl_xor(u4, 8);
    // merge the four 16-lane groups
    t4 += __shfl_xor(t4, 16);
    t4 += __shfl_xor(t4, 32);

    if (lane < 16) {
        const int c = (b0 ? 8 : 0) + (b1 ? 4 : 0) + (b2 ? 2 : 0) + (b3 ? 1 : 0);
        const float inv = 1.0f / (den + 1e-16f);
        h2[(size_t)d * 16 + c] = elu_f(t4 * inv + bias2[c]);
    }
}

// ---------------- fused mean-pool + MLP: one block per graph -------------------
__global__ __launch_bounds__(256) void k_pool_mlp(
    const float* __restrict__ h2, const int* __restrict__ batch,
    const float* __restrict__ w1, const float* __restrict__ b1,
    const float* __restrict__ w2, const float* __restrict__ b2,
    const float* __restrict__ w3, const float* __restrict__ b3,
    float* __restrict__ out)
{
    __shared__ int se[2];
    __shared__ float sm[256];
    __shared__ float hb[16], t1s[32], t2s[16];
    const int b = blockIdx.x, tid = threadIdx.x;
    if (tid < 2) {
        int key = b + tid, lo = 0, hi = NN;
        while (lo < hi) {
            int mid = (lo + hi) >> 1;
            if (batch[mid] < key) lo = mid + 1; else hi = mid;
        }
        se[tid] = lo;
    }
    __syncthreads();
    const int s = se[0], e = se[1];
    const int c = tid & 15, slot = tid >> 4;
    float acc = 0.f;
    for (int n = s + slot; n < e; n += 16) acc += h2[(size_t)n * 16 + c];
    sm[tid] = acc;
    __syncthreads();
    for (int ofs = 128; ofs >= 16; ofs >>= 1) {
        if (tid < ofs) sm[tid] += sm[tid + ofs];
        __syncthreads();
    }
    if (tid < 16) hb[tid] = sm[tid] / fmaxf((float)(e - s), 1.0f);
    __syncthreads();
    if (tid < 32) {
        float v = b1[tid];
        for (int k = 0; k < 16; ++k) v += hb[k] * w1[k * 32 + tid];
        t1s[tid] = elu_f(v);
    }
    __syncthreads();
    if (tid < 16) {
        float v = b2[tid];
        for (int k = 0; k < 32; ++k) v += t1s[k] * w2[k * 16 + tid];
        t2s[tid] = elu_f(v);
    }
    __syncthreads();
    if (tid < 32) {
        float v = b3[tid];
        for (int k = 0; k < 16; ++k) v += t2s[k] * w3[k * 32 + tid];
        out[b * 32 + tid] = v;
    }
}

// ---------------- launch -------------------------------------------------------
extern "C" void kernel_launch(void* const* d_in, const int* in_sizes, int n_in,
                              void* d_out, int out_size, void* d_ws, size_t ws_size,
                              hipStream_t stream)
{
    const float* x     = (const float*)d_in[0];
    const int*   ei    = (const int*)d_in[1];
    const int*   batch = (const int*)d_in[2];
    const float* wl1   = (const float*)d_in[3];
    const float* bl1   = (const float*)d_in[4];
    const float* wr1   = (const float*)d_in[5];
    const float* br1   = (const float*)d_in[6];
    const float* att1  = (const float*)d_in[7];
    const float* bias1 = (const float*)d_in[8];
    const float* wl2   = (const float*)d_in[9];
    const float* bl2   = (const float*)d_in[10];
    const float* wr2   = (const float*)d_in[11];
    const float* br2   = (const float*)d_in[12];
    const float* att2  = (const float*)d_in[13];
    const float* bias2 = (const float*)d_in[14];
    const float* wm1   = (const float*)d_in[15];
    const float* bm1   = (const float*)d_in[16];
    const float* wm2   = (const float*)d_in[17];
    const float* bm2   = (const float*)d_in[18];
    const float* wm3   = (const float*)d_in[19];
    const float* bm3   = (const float*)d_in[20];
    float* out = (float*)d_out;

    char* base = (char*)d_ws;
    size_t off = 0;
    auto alloc = [&](size_t bytes) -> void* {
        void* p = base + off;
        off += (bytes + 255) & ~(size_t)255;
        return p;
    };
    __half* xl1  = (__half*)alloc((size_t)NN * 128 * 2);
    float* xr1   = (float*)alloc((size_t)NN * 128 * 4);
    int*   slist = (int*)  alloc((size_t)EP * 4);
    unsigned int* bb = (unsigned int*)alloc((size_t)NBKT * CAP * 4);
    int*   rowp  = (int*)  alloc((size_t)(NN + 1) * 4);
    int*   bcursor=(int*)  alloc((size_t)NBKT * 4);
    __half* xl2  = (__half*)alloc((size_t)NN * 16 * 2);
    float* xr2   = (float*)alloc((size_t)NN * 16 * 4);
    float* h2    = (float*)alloc((size_t)NN * 16 * 4);

    (void)hipMemsetAsync(bcursor, 0, (size_t)NBKT * 4, stream);
    k_gemm1_bucket<<<G1 + EBLK, 256, 0, stream>>>(x, wl1, bl1, wr1, br1, xl1, xr1,
                                                  ei, bcursor, bb);
    k_bfinal<<<NBKT, 256, 0, stream>>>(bb, bcursor, rowp, slist);
    k_conv1_agg<<<(NN * 64) / 256, 256, 0, stream>>>(xl1, xr1, att1, bias1, rowp, slist,
                                                     wl2, bl2, wr2, br2, xl2, xr2);
    k_conv2_agg<<<(NN * 64) / 256, 256, 0, stream>>>(xl2, xr2, att2, bias2, rowp, slist, h2);
    k_pool_mlp<<<NB, 256, 0, stream>>>(h2, batch, wm1, bm1, wm2, bm2, wm3, bm3, out);
}

// Round 22
// 278.718 us; speedup vs baseline: 1.0293x; 1.0053x over previous
//
#include <hip/hip_runtime.h>
#include <hip/hip_bf16.h>
#include <hip/hip_fp16.h>
#include <math.h>

#define NN   50000
#define NE   1600000
#define EP   (NE + NN)       // edges + self loops = 1,650,000
#define NB   256
#define BK_SH 6              // 64 dsts per bucket
#define BKN  (1 << BK_SH)
#define NBKT ((NN + BKN - 1) >> BK_SH)   // 782
#define CAP_SH 12            // 4096 entries per bucket region (mean 2046)
#define CAP  (1 << CAP_SH)
#define ET   8               // edges per thread in bucket part (short chains)
#define EB   (256 * ET)      // 2048 edges per block
#define EBLK ((NE + EB - 1) / EB)    // 782 blocks
#define G1   ((NN + 31) / 32)        // 1563 gemm1 blocks

__device__ __forceinline__ float elu_f(float x)   { return x > 0.0f ? x : expm1f(x); }
// leaky_relu(x, 0.2) == max(x, 0.2x) since 0.2 > 0
__device__ __forceinline__ float lrelu_f(float x) { return fmaxf(x, 0.2f * x); }

// packed fp16 / fp32 via native clang ext-vector ops
typedef _Float16 f16x2 __attribute__((ext_vector_type(2)));
typedef float    f32x2 __attribute__((ext_vector_type(2)));

// ---------------- fused: gemm1 (blocks < G1) ∥ bucket scatter (rest) -----------
__global__ __launch_bounds__(256) void k_gemm1_bucket(
    const float* __restrict__ x, const float* __restrict__ wl,
    const float* __restrict__ bl, const float* __restrict__ wr,
    const float* __restrict__ br, __half* __restrict__ xl1, float* __restrict__ xr1,
    const int* __restrict__ ei, int* __restrict__ bcursor,
    unsigned int* __restrict__ bb)
{
    __shared__ float xs[32 * 64];
    __shared__ int lh[NBKT];
    __shared__ int cur[NBKT];
    const int tid = threadIdx.x;

    if (blockIdx.x < G1) {
        // ---------- GEMM1: xl1(half) = x@wl1+bl1, xr1(f32) = x@wr1+br1 ----------
        const int n0  = blockIdx.x * 32;
        const int nrem = min(32, NN - n0);

        const float4* xg = (const float4*)(x + (size_t)n0 * 64);
        float4* xs4 = (float4*)xs;
        const int lim4 = nrem * 16;
        for (int i = tid; i < lim4; i += 256) xs4[i] = xg[i];
        __syncthreads();

        const int g  = tid >> 6;        // 0..3 -> rows 8g..8g+7
        const int c0 = (tid & 63) * 4;  // 0..252
        const bool isl = (c0 < 128);
        const float* w  = isl ? wl : wr;
        const float* b  = isl ? bl : br;
        const int    cw = isl ? c0 : (c0 - 128);

        float4 acc[8];
#pragma unroll
        for (int r = 0; r < 8; ++r) acc[r] = make_float4(0.f, 0.f, 0.f, 0.f);

        for (int k4 = 0; k4 < 16; ++k4) {
            const float4 w0 = *(const float4*)&w[(k4*4+0)*128 + cw];
            const float4 w1 = *(const float4*)&w[(k4*4+1)*128 + cw];
            const float4 w2 = *(const float4*)&w[(k4*4+2)*128 + cw];
            const float4 w3 = *(const float4*)&w[(k4*4+3)*128 + cw];
#pragma unroll
            for (int r = 0; r < 8; ++r) {
                const float4 xv = xs4[(g*8+r)*16 + k4];
                acc[r].x += xv.x*w0.x + xv.y*w1.x + xv.z*w2.x + xv.w*w3.x;
                acc[r].y += xv.x*w0.y + xv.y*w1.y + xv.z*w2.y + xv.w*w3.y;
                acc[r].z += xv.x*w0.z + xv.y*w1.z + xv.z*w2.z + xv.w*w3.z;
                acc[r].w += xv.x*w0.w + xv.y*w1.w + xv.z*w2.w + xv.w*w3.w;
            }
        }
        const float4 bv = *(const float4*)&b[cw];
#pragma unroll
        for (int r = 0; r < 8; ++r) {
            const int row = g*8 + r;
            if (row < nrem) {
                float4 o = make_float4(acc[r].x + bv.x, acc[r].y + bv.y,
                                       acc[r].z + bv.z, acc[r].w + bv.w);
                if (isl) {
                    __half2* dst = (__half2*)&xl1[(size_t)(n0 + row) * 128 + cw];
                    dst[0] = __floats2half2_rn(o.x, o.y);
                    dst[1] = __floats2half2_rn(o.z, o.w);
                } else {
                    *(float4*)&xr1[(size_t)(n0 + row) * 128 + cw] = o;
                }
            }
        }
    } else {
        // ---------- bucket: scatter packed u32 ((d&63)<<17 | src) ---------------
        const int bid = blockIdx.x - G1;
        for (int i = tid; i < NBKT; i += 256) lh[i] = 0;
        __syncthreads();

        const int t = bid * 256 + tid;
        const bool act = (t * ET < NE);
        int4 dreg[ET / 4];
        if (act) {
            const int4* dp = (const int4*)&ei[NE + t * ET];
#pragma unroll
            for (int q = 0; q < ET / 4; ++q) {
                dreg[q] = dp[q];
                atomicAdd(&lh[dreg[q].x >> BK_SH], 1);
                atomicAdd(&lh[dreg[q].y >> BK_SH], 1);
                atomicAdd(&lh[dreg[q].z >> BK_SH], 1);
                atomicAdd(&lh[dreg[q].w >> BK_SH], 1);
            }
        }
        __syncthreads();
        for (int i = tid; i < NBKT; i += 256) {
            int h = lh[i];
            if (h > 0) cur[i] = (i << CAP_SH) + atomicAdd(&bcursor[i], h);
        }
        __syncthreads();
        if (act) {
            const int4* sp = (const int4*)&ei[t * ET];
#pragma unroll
            for (int q = 0; q < ET / 4; ++q) {
                int4 s = sp[q];
                int4 d = dreg[q];
                int bkt, p;
                bkt = d.x >> BK_SH; p = atomicAdd(&cur[bkt], 1);
                if (p < ((bkt + 1) << CAP_SH))
                    bb[p] = ((unsigned)(d.x & (BKN-1)) << 17) | (unsigned)s.x;
                bkt = d.y >> BK_SH; p = atomicAdd(&cur[bkt], 1);
                if (p < ((bkt + 1) << CAP_SH))
                    bb[p] = ((unsigned)(d.y & (BKN-1)) << 17) | (unsigned)s.y;
                bkt = d.z >> BK_SH; p = atomicAdd(&cur[bkt], 1);
                if (p < ((bkt + 1) << CAP_SH))
                    bb[p] = ((unsigned)(d.z & (BKN-1)) << 17) | (unsigned)s.z;
                bkt = d.w >> BK_SH; p = atomicAdd(&cur[bkt], 1);
                if (p < ((bkt + 1) << CAP_SH))
                    bb[p] = ((unsigned)(d.w & (BKN-1)) << 17) | (unsigned)s.w;
            }
        }
    }
}

// bfinal: one block per bucket (64 dsts). bcursor[b] holds the raw count.
__global__ __launch_bounds__(256) void k_bfinal(
    const unsigned int* __restrict__ bb, const int* __restrict__ bcursor,
    int* __restrict__ rowp, int* __restrict__ slist)
{
    __shared__ int cnt[BKN], cur[BKN];
    __shared__ int red[256];
    const int b = blockIdx.x, tid = threadIdx.x;
    const int db0 = b << BK_SH;
    const int dn  = min(BKN, NN - db0);

    // prefix over preceding buckets (<=4 iterations)
    int part = 0;
    for (int i = tid; i < b; i += 256)
        part += min(bcursor[i], CAP);
    red[tid] = part;
    __syncthreads();
    for (int ofs = 128; ofs >= 1; ofs >>= 1) {
        if (tid < ofs) red[tid] += red[tid + ofs];
        __syncthreads();
    }
    const int ebeg = red[0];
    const int count = min(bcursor[b], CAP);
    const unsigned int* src = bb + ((size_t)b << CAP_SH);
    const int out0 = ebeg + db0;

    int c0 = 0;
    if (tid < BKN) {
        c0 = (tid < dn) ? 1 : 0;       // self-loop
        cnt[tid] = c0;
    }
    __syncthreads();
    for (int i = tid; i < count; i += 256)
        atomicAdd(&cnt[src[i] >> 17], 1);
    __syncthreads();
    if (tid < BKN) c0 = cnt[tid];      // per-dst total (incl. self-loop)
    // inclusive scan of cnt[BKN]
    for (int ofs = 1; ofs < BKN; ofs <<= 1) {
        int v = 0;
        if (tid < BKN && tid >= ofs) v = cnt[tid - ofs];
        __syncthreads();
        if (tid < BKN) cnt[tid] += v;
        __syncthreads();
    }
    if (tid < BKN) {
        int ex = cnt[tid] - c0;        // exclusive
        cur[tid] = ex + 1;             // slot 0 reserved for self-loop
        if (tid < dn) {
            rowp[db0 + tid] = out0 + ex;
            slist[out0 + ex] = db0 + tid;   // self-loop
        }
    }
    if (b == 0 && tid == 0) rowp[NN] = EP;
    __syncthreads();
    for (int i = tid; i < count; i += 256) {
        unsigned u = src[i];
        int p = atomicAdd(&cur[u >> 17], 1);
        slist[out0 + p] = (int)(u & 0x1FFFFu);
    }
}

// ---------------- conv1 aggregation + fused GEMM2 ------------------------------
// Score path packed fp16; weighted accumulation packed fp32 (v_pk_fma_f32,
// bitwise-identical to scalar fp32 fma).
__global__ __launch_bounds__(256) void k_conv1_agg(
    const __half* __restrict__ xl1, const float* __restrict__ xr1,
    const float* __restrict__ att, const float* __restrict__ bias1,
    const int* __restrict__ rowp, const int* __restrict__ slist,
    const float* __restrict__ wl2, const float* __restrict__ bl2,
    const float* __restrict__ wr2, const float* __restrict__ br2,
    __half* __restrict__ xl2, float* __restrict__ xr2)
{
    __shared__ float wcombt[32 * 132];  // [j][c] transposed, stride 132
    __shared__ float bcomb[32];
    __shared__ float h1rows[4 * 128];
    const int tid = threadIdx.x;

    // stage gemm2 weights transposed (barrier below covers visibility)
    for (int i = tid; i < 2048; i += 256) {
        const int cc = i >> 4, jj = i & 15;
        wcombt[jj * 132 + cc]        = wl2[i];
        wcombt[(16 + jj) * 132 + cc] = wr2[i];
    }
    if (tid < 16) { bcomb[tid] = bl2[tid]; bcomb[16 + tid] = br2[tid]; }

    const int d = (blockIdx.x * 256 + tid) >> 6;   // wave id = dst (< NN always)
    const int lane = tid & 63;
    const int h = lane >> 3, e = lane & 7;
    const int cb = h * 16;

    f16x2 xrh[8], ath[8];
    {
        const float4* xrp = (const float4*)&xr1[(size_t)d * 128 + cb];
        const float4* atp = (const float4*)&att[cb];
#pragma unroll
        for (int q = 0; q < 4; ++q) {
            float4 a4 = xrp[q];
            xrh[2*q]   = (f16x2){(_Float16)a4.x, (_Float16)a4.y};
            xrh[2*q+1] = (f16x2){(_Float16)a4.z, (_Float16)a4.w};
            float4 b4 = atp[q];
            ath[2*q]   = (f16x2){(_Float16)b4.x, (_Float16)b4.y};
            ath[2*q+1] = (f16x2){(_Float16)b4.z, (_Float16)b4.w};
        }
    }
    const f16x2 c02 = {(_Float16)0.2f, (_Float16)0.2f};

    const int beg = rowp[d], end = rowp[d + 1];

    float den = 0.f;
    f32x2 a2[8];
#pragma unroll
    for (int q = 0; q < 8; ++q) a2[q] = (f32x2){0.f, 0.f};

    for (int base = beg; base < end; base += 64) {
        const int nb = min(64, end - base);
        int sv = (lane < nb) ? slist[base + lane] : 0;
        for (int c8 = 0; c8 * 8 < nb; c8 += 2) {
            const int idx0 = c8 * 8 + e;
            const int idx1 = idx0 + 8;           // <= 63 always (c8 even, <8)
            const int s0 = __shfl(sv, idx0);
            const int s1 = __shfl(sv, idx1 & 63);
            const bool e0 = (idx0 < nb), e1 = (idx1 < nb);
            float4 p0, p1, q0, q1;
            if (e0) {
                const float4* vp = (const float4*)(xl1 + (size_t)s0 * 128 + cb);
                p0 = vp[0]; p1 = vp[1];
            }
            if (e1) {
                const float4* vp = (const float4*)(xl1 + (size_t)s1 * 128 + cb);
                q0 = vp[0]; q1 = vp[1];
            }
            if (e0) {
                const f16x2* hh = (const f16x2*)&p0;   // 4 packed pairs
                const f16x2* hg = (const f16x2*)&p1;
                float s = 0.f;
#pragma unroll
                for (int q = 0; q < 4; ++q) {
                    f16x2 t = hh[q] + xrh[q];
                    t = __builtin_elementwise_max(t, t * c02);
                    s = __builtin_amdgcn_fdot2(ath[q], t, s, false);
                }
#pragma unroll
                for (int q = 0; q < 4; ++q) {
                    f16x2 t = hg[q] + xrh[4+q];
                    t = __builtin_elementwise_max(t, t * c02);
                    s = __builtin_amdgcn_fdot2(ath[4+q], t, s, false);
                }
                const float w = __expf(fminf(s, 80.f));
                den += w;
                const f32x2 w2 = {w, w};
#pragma unroll
                for (int q = 0; q < 4; ++q) {
                    a2[q]   += w2 * (f32x2){(float)hh[q].x, (float)hh[q].y};
                    a2[4+q] += w2 * (f32x2){(float)hg[q].x, (float)hg[q].y};
                }
            }
            if (e1) {
                const f16x2* hh = (const f16x2*)&q0;
                const f16x2* hg = (const f16x2*)&q1;
                float s = 0.f;
#pragma unroll
                for (int q = 0; q < 4; ++q) {
                    f16x2 t = hh[q] + xrh[q];
                    t = __builtin_elementwise_max(t, t * c02);
                    s = __builtin_amdgcn_fdot2(ath[q], t, s, false);
                }
#pragma unroll
                for (int q = 0; q < 4; ++q) {
                    f16x2 t = hg[q] + xrh[4+q];
                    t = __builtin_elementwise_max(t, t * c02);
                    s = __builtin_amdgcn_fdot2(ath[4+q], t, s, false);
                }
                const float w = __expf(fminf(s, 80.f));
                den += w;
                const f32x2 w2 = {w, w};
#pragma unroll
                for (int q = 0; q < 4; ++q) {
                    a2[q]   += w2 * (f32x2){(float)hh[q].x, (float)hh[q].y};
                    a2[4+q] += w2 * (f32x2){(float)hg[q].x, (float)hg[q].y};
                }
            }
        }
    }

    float a[16];
#pragma unroll
    for (int j = 0; j < 16; ++j) a[j] = a2[j >> 1][j & 1];

    // sum den over the 8 e-lanes of this head
    den += __shfl_xor(den, 1);
    den += __shfl_xor(den, 2);
    den += __shfl_xor(den, 4);

    // reduce-scatter a[16] over e-lanes: each level halves the channel set
    const bool b0 = (e & 1), b1 = (e & 2), b2 = (e & 4);
    float t1[8], u1[8];
#pragma unroll
    for (int j = 0; j < 8; ++j) {
        t1[j] = b0 ? a[j + 8] : a[j];
        u1[j] = b0 ? a[j] : a[j + 8];
    }
#pragma unroll
    for (int j = 0; j < 8; ++j) t1[j] += __shfl_xor(u1[j], 1);
    float t2[4], u2[4];
#pragma unroll
    for (int j = 0; j < 4; ++j) {
        t2[j] = b1 ? t1[j + 4] : t1[j];
        u2[j] = b1 ? t1[j] : t1[j + 4];
    }
#pragma unroll
    for (int j = 0; j < 4; ++j) t2[j] += __shfl_xor(u2[j], 2);
    float t3[2], u3[2];
#pragma unroll
    for (int j = 0; j < 2; ++j) {
        t3[j] = b2 ? t2[j + 2] : t2[j];
        u3[j] = b2 ? t2[j] : t2[j + 2];
    }
#pragma unroll
    for (int j = 0; j < 2; ++j) t3[j] += __shfl_xor(u3[j], 4);

    const int c0 = (b0 ? 8 : 0) + (b1 ? 4 : 0) + (b2 ? 2 : 0);
    const float inv = 1.0f / (den + 1e-16f);
    const int c = cb + c0;                 // even -> 8B-aligned float2 store
    const float o0 = elu_f(t3[0] * inv + bias1[c]);
    const float o1 = elu_f(t3[1] * inv + bias1[c + 1]);

    // ---- fused GEMM2 epilogue (vectorized) ----
    const int wv = tid >> 6;
    *(float2*)&h1rows[wv * 128 + c] = make_float2(o0, o1);
    __syncthreads();
    {
        const int j = lane & 31;          // output column 0..31
        const int half = lane >> 5;       // channel half 0/1
        const float* hr = &h1rows[wv * 128 + half * 64];
        const float* wc = &wcombt[j * 132 + half * 64];
        float sum = 0.f;
#pragma unroll
        for (int cc = 0; cc < 64; cc += 4) {
            const float4 hv = *(const float4*)&hr[cc];
            const float4 wv4 = *(const float4*)&wc[cc];
            sum += hv.x*wv4.x + hv.y*wv4.y + hv.z*wv4.z + hv.w*wv4.w;
        }
        sum += __shfl_xor(sum, 32);
        if (half == 0) {
            sum += bcomb[j];
            if (j < 16) xl2[(size_t)d * 16 + j] = __float2half(sum);
            else        xr2[(size_t)d * 16 + (j - 16)] = sum;
        }
    }
}

// ---------------- conv2 aggregation: one EDGE per lane -------------------------
__global__ __launch_bounds__(256) void k_conv2_agg(
    const __half* __restrict__ xl2, const float* __restrict__ xr2,
    const float* __restrict__ att, const float* __restrict__ bias2,
    const int* __restrict__ rowp, const int* __restrict__ slist,
    float* __restrict__ h2)
{
    const int d = (blockIdx.x * 256 + threadIdx.x) >> 6;   // wave id = dst
    if (d >= NN) return;
    const int lane = threadIdx.x & 63;

    f16x2 xrh[8], ath[8];
    {
        const float4* xrp = (const float4*)&xr2[(size_t)d * 16];
        const float4* atp = (const float4*)&att[0];
#pragma unroll
        for (int q = 0; q < 4; ++q) {
            float4 a4 = xrp[q];
            xrh[2*q]   = (f16x2){(_Float16)a4.x, (_Float16)a4.y};
            xrh[2*q+1] = (f16x2){(_Float16)a4.z, (_Float16)a4.w};
            float4 b4 = atp[q];
            ath[2*q]   = (f16x2){(_Float16)b4.x, (_Float16)b4.y};
            ath[2*q+1] = (f16x2){(_Float16)b4.z, (_Float16)b4.w};
        }
    }
    const f16x2 c02 = {(_Float16)0.2f, (_Float16)0.2f};

    const int beg = rowp[d];
    const int total = rowp[d + 1] - beg;

    float den = 0.f;
    f32x2 a2[8];
#pragma unroll
    for (int q = 0; q < 8; ++q) a2[q] = (f32x2){0.f, 0.f};

    for (int j = lane; j < total; j += 64) {
        const int src = slist[beg + j];                 // coalesced
        const float4* vp = (const float4*)(xl2 + (size_t)src * 16);
        const float4 r0 = vp[0], r1 = vp[1];            // 16 halves
        const f16x2* hh = (const f16x2*)&r0;
        const f16x2* hg = (const f16x2*)&r1;
        float s = 0.f;
#pragma unroll
        for (int q = 0; q < 4; ++q) {
            f16x2 t = hh[q] + xrh[q];
            t = __builtin_elementwise_max(t, t * c02);
            s = __builtin_amdgcn_fdot2(ath[q], t, s, false);
        }
#pragma unroll
        for (int q = 0; q < 4; ++q) {
            f16x2 t = hg[q] + xrh[4+q];
            t = __builtin_elementwise_max(t, t * c02);
            s = __builtin_amdgcn_fdot2(ath[4+q], t, s, false);
        }
        const float w = __expf(fminf(s, 80.f));
        den += w;
        const f32x2 w2 = {w, w};
#pragma unroll
        for (int q = 0; q < 4; ++q) {
            a2[q]   += w2 * (f32x2){(float)hh[q].x, (float)hh[q].y};
            a2[4+q] += w2 * (f32x2){(float)hg[q].x, (float)hg[q].y};
        }
    }

    float a[16];
#pragma unroll
    for (int j = 0; j < 16; ++j) a[j] = a2[j >> 1][j & 1];

    // full-wave den sum
    den += __shfl_xor(den, 1);
    den += __shfl_xor(den, 2);
    den += __shfl_xor(den, 4);
    den += __shfl_xor(den, 8);
    den += __shfl_xor(den, 16);
    den += __shfl_xor(den, 32);

    // reduce-scatter a[16] over lane bits 0..3, then plain-sum xor 16,32
    const bool b0 = (lane & 1), b1 = (lane & 2), b2 = (lane & 4), b3 = (lane & 8);
    float t1[8], u1[8];
#pragma unroll
    for (int j = 0; j < 8; ++j) {
        t1[j] = b0 ? a[j + 8] : a[j];
        u1[j] = b0 ? a[j] : a[j + 8];
    }
#pragma unroll
    for (int j = 0; j < 8; ++j) t1[j] += __shfl_xor(u1[j], 1);
    float t2[4], u2[4];
#pragma unroll
    for (int j = 0; j < 4; ++j) {
        t2[j] = b1 ? t1[j + 4] : t1[j];
        u2[j] = b1 ? t1[j] : t1[j + 4];
    }
#pragma unroll
    for (int j = 0; j < 4; ++j) t2[j] += __shfl_xor(u2[j], 2);
    float t3[2], u3[2];
#pragma unroll
    for (int j = 0; j < 2; ++j) {
        t3[j] = b2 ? t2[j + 2] : t2[j];
        u3[j] = b2 ? t2[j] : t2[j + 2];
    }
#pragma unroll
    for (int j = 0; j < 2; ++j) t3[j] += __shfl_xor(u3[j], 4);
    float t4 = b3 ? t3[1] : t3[0];
    float u4 = b3 ? t3[0] : t3[1];
    t4 += __shfl_xor(u4, 8);
    // merge the four 16-lane groups
    t4 += __shfl_xor(t4, 16);
    t4 += __shfl_xor(t4, 32);

    if (lane < 16) {
        const int c = (b0 ? 8 : 0) + (b1 ? 4 : 0) + (b2 ? 2 : 0) + (b3 ? 1 : 0);
        const float inv = 1.0f / (den + 1e-16f);
        h2[(size_t)d * 16 + c] = elu_f(t4 * inv + bias2[c]);
    }
}

// ---------------- fused mean-pool + MLP: one block per graph -------------------
__global__ __launch_bounds__(256) void k_pool_mlp(
    const float* __restrict__ h2, const int* __restrict__ batch,
    const float* __restrict__ w1, const float* __restrict__ b1,
    const float* __restrict__ w2, const float* __restrict__ b2,
    const float* __restrict__ w3, const float* __restrict__ b3,
    float* __restrict__ out)
{
    __shared__ int se[2];
    __shared__ float sm[256];
    __shared__ float hb[16], t1s[32], t2s[16];
    const int b = blockIdx.x, tid = threadIdx.x;
    if (tid < 2) {
        int key = b + tid, lo = 0, hi = NN;
        while (lo < hi) {
            int mid = (lo + hi) >> 1;
            if (batch[mid] < key) lo = mid + 1; else hi = mid;
        }
        se[tid] = lo;
    }
    __syncthreads();
    const int s = se[0], e = se[1];
    const int c = tid & 15, slot = tid >> 4;
    float acc = 0.f;
    for (int n = s + slot; n < e; n += 16) acc += h2[(size_t)n * 16 + c];
    sm[tid] = acc;
    __syncthreads();
    for (int ofs = 128; ofs >= 16; ofs >>= 1) {
        if (tid < ofs) sm[tid] += sm[tid + ofs];
        __syncthreads();
    }
    if (tid < 16) hb[tid] = sm[tid] / fmaxf((float)(e - s), 1.0f);
    __syncthreads();
    if (tid < 32) {
        float v = b1[tid];
        for (int k = 0; k < 16; ++k) v += hb[k] * w1[k * 32 + tid];
        t1s[tid] = elu_f(v);
    }
    __syncthreads();
    if (tid < 16) {
        float v = b2[tid];
        for (int k = 0; k < 32; ++k) v += t1s[k] * w2[k * 16 + tid];
        t2s[tid] = elu_f(v);
    }
    __syncthreads();
    if (tid < 32) {
        float v = b3[tid];
        for (int k = 0; k < 16; ++k) v += t2s[k] * w3[k * 32 + tid];
        out[b * 32 + tid] = v;
    }
}

// ---------------- launch -------------------------------------------------------
extern "C" void kernel_launch(void* const* d_in, const int* in_sizes, int n_in,
                              void* d_out, int out_size, void* d_ws, size_t ws_size,
                              hipStream_t stream)
{
    const float* x     = (const float*)d_in[0];
    const int*   ei    = (const int*)d_in[1];
    const int*   batch = (const int*)d_in[2];
    const float* wl1   = (const float*)d_in[3];
    const float* bl1   = (const float*)d_in[4];
    const float* wr1   = (const float*)d_in[5];
    const float* br1   = (const float*)d_in[6];
    const float* att1  = (const float*)d_in[7];
    const float* bias1 = (const float*)d_in[8];
    const float* wl2   = (const float*)d_in[9];
    const float* bl2   = (const float*)d_in[10];
    const float* wr2   = (const float*)d_in[11];
    const float* br2   = (const float*)d_in[12];
    const float* att2  = (const float*)d_in[13];
    const float* bias2 = (const float*)d_in[14];
    const float* wm1   = (const float*)d_in[15];
    const float* bm1   = (const float*)d_in[16];
    const float* wm2   = (const float*)d_in[17];
    const float* bm2   = (const float*)d_in[18];
    const float* wm3   = (const float*)d_in[19];
    const float* bm3   = (const float*)d_in[20];
    float* out = (float*)d_out;

    char* base = (char*)d_ws;
    size_t off = 0;
    auto alloc = [&](size_t bytes) -> void* {
        void* p = base + off;
        off += (bytes + 255) & ~(size_t)255;
        return p;
    };
    __half* xl1  = (__half*)alloc((size_t)NN * 128 * 2);
    float* xr1   = (float*)alloc((size_t)NN * 128 * 4);
    int*   slist = (int*)  alloc((size_t)EP * 4);
    unsigned int* bb = (unsigned int*)alloc((size_t)NBKT * CAP * 4);
    int*   rowp  = (int*)  alloc((size_t)(NN + 1) * 4);
    int*   bcursor=(int*)  alloc((size_t)NBKT * 4);
    __half* xl2  = (__half*)alloc((size_t)NN * 16 * 2);
    float* xr2   = (float*)alloc((size_t)NN * 16 * 4);
    float* h2    = (float*)alloc((size_t)NN * 16 * 4);

    (void)hipMemsetAsync(bcursor, 0, (size_t)NBKT * 4, stream);
    k_gemm1_bucket<<<G1 + EBLK, 256, 0, stream>>>(x, wl1, bl1, wr1, br1, xl1, xr1,
                                                  ei, bcursor, bb);
    k_bfinal<<<NBKT, 256, 0, stream>>>(bb, bcursor, rowp, slist);
    k_conv1_agg<<<(NN * 64) / 256, 256, 0, stream>>>(xl1, xr1, att1, bias1, rowp, slist,
                                                     wl2, bl2, wr2, br2, xl2, xr2);
    k_conv2_agg<<<(NN * 64) / 256, 256, 0, stream>>>(xl2, xr2, att2, bias2, rowp, slist, h2);
    k_pool_mlp<<<NB, 256, 0, stream>>>(h2, batch, wm1, bm1, wm2, bm2, wm3, bm3, out);
}